// Round 2
// baseline (2124.479 us; speedup 1.0000x reference)
//
#include <hip/hip_runtime.h>
#include <hip/hip_bf16.h>

// DS_ODE: K=3 ensemble, B=32, N=5, T=20, S=4, H=64, D=1280, DFF=2560, L=6.
// Inputs/outputs are FP32 (per reference setup_inputs). ODE + mu chain in pure
// fp32 (outputs 1/2 exact); transformer GEMMs in bf16 MFMA with fp32 accum.

using bf16 = __hip_bfloat16;
typedef unsigned short u16;
typedef __bf16 bf16x8 __attribute__((ext_vector_type(8)));
typedef float f32x4 __attribute__((ext_vector_type(4)));

#define DEV_INLINE __device__ __forceinline__

DEV_INLINE bf16 f2bf(float v) { return __float2bfloat16(v); }
DEV_INLINE u16 f2bfu(float v) {
  bf16 h = __float2bfloat16(v);
  return *(u16*)&h;
}
DEV_INLINE float rlf(float v, int lane) {
  return __uint_as_float(__builtin_amdgcn_readlane(__float_as_uint(v), lane));
}
DEV_INLINE float ftanh(float x) {
  float ax = fminf(fabsf(x), 15.f);
  float e = __expf(-2.f * ax);
  float r = (1.f - e) * __builtin_amdgcn_rcpf(1.f + e);
  return x < 0.f ? -r : r;
}
DEV_INLINE float fsig(float x) {
  return __builtin_amdgcn_rcpf(1.f + __expf(-x));
}

// ---------------- workspace layout ----------------
// bf16 (u16) transposed-weight scratch, reused per layer:
constexpr size_t SLICE_DD = 1280 * 1280;          // 1,638,400
constexpr size_t SLICE_DF = 1280 * 2560;          // 3,276,800
constexpr size_t WT_Q   = 0;                      // Q  (n=1280, k=1280)
constexpr size_t WT_K   = SLICE_DD;               // K
constexpr size_t WT_V   = 2 * SLICE_DD;           // V
constexpr size_t WT_O   = 3 * SLICE_DD;           // O
constexpr size_t WT_F1  = 4 * SLICE_DD;           // FF1^T (n=2560, k=1280)
constexpr size_t WT_F2  = WT_F1 + SLICE_DF;       // FF2^T (n=1280, k=2560)
constexpr size_t WT_OUT = WT_F2 + SLICE_DF;       // Wout^T (n=160, k=1280)
constexpr size_t WT_END = WT_OUT + 160 * 1280;    // 13,312,000 u16
constexpr size_t FOFF   = WT_END * 2;             // byte offset of fp32 region
// fp32 element offsets:
constexpr size_t F_ZT = 0;                        // z_t: 480*20*64
constexpr size_t F_XF = F_ZT + 614400;            // x master fp32 480*1280
constexpr size_t F_Q  = F_XF + 614400;
constexpr size_t F_K  = F_Q + 614400;
constexpr size_t F_V  = F_K + 614400;
constexpr size_t F_T1 = F_V + 614400;             // gemm out scratch 480*2560
constexpr size_t F_END = F_T1 + 1228800;
constexpr size_t HOFF = FOFF + F_END * 4;         // byte offset of bf16 acts
constexpr size_t H_XH = 0;                        // x bf16 480*1280
constexpr size_t H_OH = 614400;                   // attn out bf16 480*1280
constexpr size_t H_FF = 1228800;                  // relu(ff1) bf16 480*2560

// ---------------- per-layer weight transpose + fp32->bf16 ----------------
// grid 13000 blocks of 256: [0,6400) Wq/Wk/Wv/Woa slice l (1280x1280),
// [6400,9600) Wff1 (1280x2560), [9600,12800) Wff2 (2560x1280),
// [12800,13000) Wout (1280x160). 32x32 tiles through LDS.
__global__ __launch_bounds__(256) void transpose_layer_kernel(
    const float* __restrict__ Wq, const float* __restrict__ Wk,
    const float* __restrict__ Wv, const float* __restrict__ Wo,
    const float* __restrict__ Wff1, const float* __restrict__ Wff2,
    const float* __restrict__ Wout, u16* __restrict__ wt, int l) {
  int bid = blockIdx.x;
  const float* src;
  u16* dst;
  int R, C, tile;
  if (bid < 6400) {
    int mat = bid / 1600;
    tile = bid % 1600;
    src = (mat == 0 ? Wq : mat == 1 ? Wk : mat == 2 ? Wv : Wo) + (size_t)l * SLICE_DD;
    dst = wt + (size_t)mat * SLICE_DD;
    R = 1280; C = 1280;
  } else if (bid < 9600) {
    tile = bid - 6400;
    src = Wff1 + (size_t)l * SLICE_DF;
    dst = wt + WT_F1;
    R = 1280; C = 2560;
  } else if (bid < 12800) {
    tile = bid - 9600;
    src = Wff2 + (size_t)l * SLICE_DF;
    dst = wt + WT_F2;
    R = 2560; C = 1280;
  } else {
    tile = bid - 12800;
    src = Wout;
    dst = wt + WT_OUT;
    R = 1280; C = 160;
  }
  int tc = C >> 5;
  int r0 = (tile / tc) << 5, c0 = (tile % tc) << 5;
  __shared__ u16 tl[32][36];
  int t = threadIdx.x;
  int rr = t >> 3, c4 = (t & 7) << 2;
  float4 v = *(const float4*)&src[(size_t)(r0 + rr) * C + (c0 + c4)];
  tl[rr][c4 + 0] = f2bfu(v.x);
  tl[rr][c4 + 1] = f2bfu(v.y);
  tl[rr][c4 + 2] = f2bfu(v.z);
  tl[rr][c4 + 3] = f2bfu(v.w);
  __syncthreads();
  ushort4 o;
  o.x = tl[c4 + 0][rr];
  o.y = tl[c4 + 1][rr];
  o.z = tl[c4 + 2][rr];
  o.w = tl[c4 + 3][rr];
  *(ushort4*)&dst[(size_t)(c0 + rr) * R + (r0 + c4)] = o;
}

// ---------------- GEMM: C[M,N] = A[M,K] @ Bt[N,K]^T + bias ----------------
// 128x128 block tile, BK=32, 4 waves each 64x64 via 4x4 16x16x32 bf16 MFMA.
// EPI: 0 = fp32 out, 1 = relu + bf16 out.
template <int EPI>
__global__ __launch_bounds__(256) void gemm_bt(
    const u16* __restrict__ A, const u16* __restrict__ Bt, size_t btz,
    const float* __restrict__ bz0, const float* __restrict__ bz1,
    const float* __restrict__ bz2, float* __restrict__ Cf,
    bf16* __restrict__ Ch, size_t outz, int M, int N, int K) {
  const int tid = threadIdx.x;
  const int l = tid & 63;
  const int wv = tid >> 6;
  const int wm = wv & 1, wn = wv >> 1;
  const int n0 = blockIdx.x * 128, m0 = blockIdx.y * 128;
  const int z = blockIdx.z;
  Bt += (size_t)z * btz;
  const float* bias = (z == 0) ? bz0 : (z == 1 ? bz1 : bz2);
  if (EPI == 0) Cf += (size_t)z * outz; else Ch += (size_t)z * outz;

  __shared__ u16 As[128 * 32];
  __shared__ u16 Bs[128 * 32];
  f32x4 acc[4][4] = {};

  for (int kt = 0; kt < K; kt += 32) {
    __syncthreads();
#pragma unroll
    for (int j = 0; j < 2; j++) {
      int idx = tid + j * 256;
      int row = idx >> 2, oct = idx & 3;
      int gr = m0 + row; gr = gr < M ? gr : M - 1;
      *(uint4*)&As[idx * 8] = *(const uint4*)&A[(size_t)gr * K + kt + oct * 8];
      int gn = n0 + row; gn = gn < N ? gn : N - 1;
      *(uint4*)&Bs[idx * 8] = *(const uint4*)&Bt[(size_t)gn * K + kt + oct * 8];
    }
    __syncthreads();
    bf16x8 af[4], bfr[4];
#pragma unroll
    for (int mt = 0; mt < 4; mt++)
      af[mt] = *(const bf16x8*)&As[(wm * 64 + mt * 16 + (l & 15)) * 32 + (l >> 4) * 8];
#pragma unroll
    for (int nt = 0; nt < 4; nt++)
      bfr[nt] = *(const bf16x8*)&Bs[(wn * 64 + nt * 16 + (l & 15)) * 32 + (l >> 4) * 8];
#pragma unroll
    for (int mt = 0; mt < 4; mt++)
#pragma unroll
      for (int nt = 0; nt < 4; nt++)
        acc[mt][nt] = __builtin_amdgcn_mfma_f32_16x16x32_bf16(af[mt], bfr[nt], acc[mt][nt], 0, 0, 0);
  }

#pragma unroll
  for (int mt = 0; mt < 4; mt++)
#pragma unroll
    for (int nt = 0; nt < 4; nt++)
#pragma unroll
      for (int r = 0; r < 4; r++) {
        int row = m0 + wm * 64 + mt * 16 + (l >> 4) * 4 + r;
        int col = n0 + wn * 64 + nt * 16 + (l & 15);
        if (row < M && col < N) {
          float v = acc[mt][nt][r] + bias[col];
          if (EPI == 1) v = fmaxf(v, 0.f);
          if (EPI == 0) Cf[(size_t)row * N + col] = v;
          else Ch[(size_t)row * N + col] = f2bf(v);
        }
      }
}

// ---------------- ODE kernel: one block (4 waves) per (kb,n) row ----------
__global__ __launch_bounds__(256) void ode_kernel(
    const float* __restrict__ data, const float* __restrict__ phy,
    const float* __restrict__ Wi1, const float* __restrict__ bi1,
    const float* __restrict__ Wi2, const float* __restrict__ bi2,
    const float* __restrict__ Wo1, const float* __restrict__ bo1,
    const float* __restrict__ Wo2, const float* __restrict__ bo2,
    float* __restrict__ z_t, float* __restrict__ out_z) {
  const int r = blockIdx.x;          // 0..479 = kb*5+n
  const int kb = r / 5, n = r % 5;
  const int kx = kb >> 5, b = kb & 31;
  const int tid = threadIdx.x;
  const int w = tid >> 6, lane = tid & 63;

  __shared__ float obs[80];          // this row's data[b][n][t][s]
  __shared__ float red0[4][64];
  __shared__ float red1[4][64];

  if (tid < 80) obs[tid] = data[(size_t)(b * 5 + n) * 80 + tid];

  // per-lane weight columns: wave w owns k-slice [16w,16w+16) plus obs row 64+w
  float w1[17], w2[16];
#pragma unroll
  for (int i = 0; i < 16; i++) w1[i] = Wo1[(w * 16 + i) * 64 + lane];
  w1[16] = Wo1[(64 + w) * 64 + lane];
#pragma unroll
  for (int i = 0; i < 16; i++) w2[i] = Wo2[(w * 16 + i) * 64 + lane];
  const float bb1 = bo1[lane];
  const float bb2 = bo2[lane];

  __syncthreads();  // obs ready

  // ---- z0 encoder (fused) ----
  float pin[14];
#pragma unroll
  for (int s = 0; s < 4; s++) pin[s] = obs[s];
  pin[4] = obs[0];
  pin[5] = obs[1];
#pragma unroll
  for (int s = 0; s < 8; s++) pin[6 + s] = phy[b * 8 + s];

  float h1 = bi1[kx * 64 + lane];
#pragma unroll
  for (int f = 0; f < 14; f++)
    h1 = fmaf(pin[f], Wi1[(kx * 14 + f) * 64 + lane], h1);
  h1 = ftanh(h1);

  float part = 0.f;
#pragma unroll
  for (int i = 0; i < 16; i++)
    part = fmaf(rlf(h1, w * 16 + i), Wi2[(size_t)(kx * 64 + w * 16 + i) * 64 + lane], part);
  red0[w][lane] = part;
  __syncthreads();
  float zz = red0[0][lane] + red0[1][lane] + red0[2][lane] + red0[3][lane] + bi2[kx * 64 + lane];

  if (w == 0) z_t[(size_t)r * 1280 + lane] = zz;  // tt = 0
  __syncthreads();  // protect red0 before first feval reuse

  auto feval = [&](float y, float ov) -> float {
    float p = 0.f;
#pragma unroll
    for (int i = 0; i < 16; i++) p = fmaf(rlf(y, w * 16 + i), w1[i], p);
    p = fmaf(ov, w1[16], p);
    red0[w][lane] = p;
    __syncthreads();
    float hh = red0[0][lane] + red0[1][lane] + red0[2][lane] + red0[3][lane] + bb1;
    hh = ftanh(hh);
    float qq = 0.f;
#pragma unroll
    for (int i = 0; i < 16; i++) qq = fmaf(rlf(hh, w * 16 + i), w2[i], qq);
    red1[w][lane] = qq;
    __syncthreads();
    return red1[0][lane] + red1[1][lane] + red1[2][lane] + red1[3][lane] + bb2;
  };

  auto interp1 = [&](float t) -> float {  // only this wave's obs feature (s=w)
    int i0 = (int)floorf(t);
    i0 = i0 < 18 ? i0 : 18;
    float fr = t - (float)i0;
    float a = obs[i0 * 4 + w];
    float c = obs[i0 * 4 + 4 + w];
    return fmaf(fr, c - a, a);
  };

  for (int j = 0; j < 190; j++) {
    float t = (float)j * 0.1f;
    float oA = interp1(t);
    float oB = interp1(t + 0.05f);
    float oC = interp1(t + 0.1f);
    float k1 = feval(zz, oA);
    float k2 = feval(fmaf(0.05f, k1, zz), oB);
    float k3 = feval(fmaf(0.05f, k2, zz), oB);
    float k4 = feval(fmaf(0.1f, k3, zz), oC);
    zz = fmaf(0.1f / 6.f, k1 + 2.f * k2 + 2.f * k3 + k4, zz);
    if (((j + 1) % 10) == 0 && w == 0) {
      int tt = (j + 1) / 10;
      z_t[(size_t)(r * 20 + tt) * 64 + lane] = zz;
      if (tt == 19) out_z[(size_t)r * 64 + lane] = zz;
    }
  }
}

// ---------------- mu / proj / gate / x-build: one wave per (kb,n,t) -------
__global__ __launch_bounds__(64) void cd_kernel(
    const float* __restrict__ data, const float* __restrict__ z_t,
    const float* __restrict__ We1, const float* __restrict__ be1,
    const float* __restrict__ We2, const float* __restrict__ be2,
    const float* __restrict__ Wfm, const float* __restrict__ bfm,
    const float* __restrict__ Wg1, const float* __restrict__ bg1,
    const float* __restrict__ Wg2, const float* __restrict__ bg2,
    float* __restrict__ xf, bf16* __restrict__ xh, float* __restrict__ out_mu) {
  const int rt = blockIdx.x;  // (kb*5+n)*20 + t
  const int lane = threadIdx.x;
  const int kb = rt / 100;
  const int rem = rt % 100;
  const int n = rem / 20, t = rem % 20;
  const int b = kb & 31, kx = kb >> 5;

  float obs4[4];
#pragma unroll
  for (int s = 0; s < 4; s++)
    obs4[s] = data[(size_t)((b * 5 + n) * 20 + t) * 4 + s];

  float mh = be1[lane];
#pragma unroll
  for (int s = 0; s < 4; s++) mh = fmaf(obs4[s], We1[s * 64 + lane], mh);
  mh = fmaxf(mh, 0.f);

  float mu = be2[lane];
#pragma unroll 16
  for (int h = 0; h < 64; h++) mu = fmaf(rlf(mh, h), We2[h * 64 + lane], mu);

  if (t == 19) out_mu[(size_t)(kb * 5 + n) * 64 + lane] = mu;

  float zv = z_t[(size_t)rt * 64 + lane];

  float pj = bfm[lane];
#pragma unroll 16
  for (int h = 0; h < 64; h++) pj = fmaf(rlf(zv, h), Wfm[h * 64 + lane], pj);
#pragma unroll 16
  for (int h = 0; h < 64; h++) pj = fmaf(rlf(mu, h), Wfm[(64 + h) * 64 + lane], pj);

  float gh = bg1[kx * 64 + lane];
#pragma unroll 16
  for (int h = 0; h < 64; h++)
    gh = fmaf(rlf(pj, h), Wg1[(size_t)(kx * 64 + h) * 64 + lane], gh);
  gh = ftanh(gh);

  float gt = bg2[kx * 64 + lane];
#pragma unroll 16
  for (int h = 0; h < 64; h++)
    gt = fmaf(rlf(gh, h), Wg2[(size_t)(kx * 64 + h) * 64 + lane], gt);
  gt = fsig(gt);

  float xv = pj * gt;
  size_t xo = (size_t)(kb * 5 + n) * 1280 + t * 64 + lane;
  xf[xo] = xv;
  xh[xo] = f2bf(xv);
}

// ---------------- attention: one wave per (kb, head) ----------------------
__global__ __launch_bounds__(64) void attn_kernel(
    const float* __restrict__ q, const float* __restrict__ k,
    const float* __restrict__ v, bf16* __restrict__ oh) {
  const int kb = blockIdx.x >> 2, h = blockIdx.x & 3;
  const int lane = threadIdx.x;
  const size_t base = (size_t)(kb * 5) * 1280 + h * 320 + lane;
  float qv[5][5], kv[5][5], vv[5][5];
#pragma unroll
  for (int i = 0; i < 5; i++)
#pragma unroll
    for (int c = 0; c < 5; c++) {
      size_t off = base + (size_t)i * 1280 + c * 64;
      qv[i][c] = q[off];
      kv[i][c] = k[off];
      vv[i][c] = v[off];
    }
  float s[5][5];
#pragma unroll
  for (int i = 0; i < 5; i++)
#pragma unroll
    for (int j = 0; j < 5; j++) {
      float a = 0.f;
#pragma unroll
      for (int c = 0; c < 5; c++) a = fmaf(qv[i][c], kv[j][c], a);
#pragma unroll
      for (int m = 1; m < 64; m <<= 1) a += __shfl_xor(a, m, 64);
      s[i][j] = a * 0.055901699437494745f;  // 1/sqrt(320)
    }
#pragma unroll
  for (int i = 0; i < 5; i++) {
    float mx = s[i][0];
#pragma unroll
    for (int j = 1; j < 5; j++) mx = fmaxf(mx, s[i][j]);
    float sum = 0.f;
#pragma unroll
    for (int j = 0; j < 5; j++) {
      s[i][j] = __expf(s[i][j] - mx);
      sum += s[i][j];
    }
    float inv = __builtin_amdgcn_rcpf(sum);
#pragma unroll
    for (int j = 0; j < 5; j++) s[i][j] *= inv;
  }
#pragma unroll
  for (int i = 0; i < 5; i++)
#pragma unroll
    for (int c = 0; c < 5; c++) {
      float a = 0.f;
#pragma unroll
      for (int j = 0; j < 5; j++) a = fmaf(s[i][j], vv[j][c], a);
      oh[base + (size_t)i * 1280 + c * 64] = f2bf(a);
    }
}

// ---------------- residual + layernorm: one block per row -----------------
__global__ __launch_bounds__(256) void ln_kernel(
    const float* __restrict__ g, float* __restrict__ xf, bf16* __restrict__ xh,
    const float* __restrict__ sc, const float* __restrict__ bi) {
  const int row = blockIdx.x, tid = threadIdx.x;
  const size_t base = (size_t)row * 1280;
  float v[5], s1 = 0.f, s2 = 0.f;
#pragma unroll
  for (int i = 0; i < 5; i++) {
    int c = tid + i * 256;
    float x = xf[base + c] + g[base + c];
    v[i] = x;
    s1 += x;
    s2 = fmaf(x, x, s2);
  }
#pragma unroll
  for (int m = 1; m < 64; m <<= 1) {
    s1 += __shfl_xor(s1, m, 64);
    s2 += __shfl_xor(s2, m, 64);
  }
  __shared__ float r1[4], r2[4];
  const int wv = tid >> 6;
  if ((tid & 63) == 0) { r1[wv] = s1; r2[wv] = s2; }
  __syncthreads();
  s1 = r1[0] + r1[1] + r1[2] + r1[3];
  s2 = r2[0] + r2[1] + r2[2] + r2[3];
  const float mean = s1 * (1.f / 1280.f);
  float var = s2 * (1.f / 1280.f) - mean * mean;
  var = fmaxf(var, 0.f);
  const float rs = rsqrtf(var + 1e-5f);
#pragma unroll
  for (int i = 0; i < 5; i++) {
    int c = tid + i * 256;
    float y = (v[i] - mean) * rs * sc[c] + bi[c];
    xf[base + c] = y;
    xh[base + c] = f2bf(y);
  }
}

// ---------------- host launcher -------------------------------------------
extern "C" void kernel_launch(void* const* d_in, const int* in_sizes, int n_in,
                              void* d_out, int out_size, void* d_ws, size_t ws_size,
                              hipStream_t stream) {
  const float* data = (const float*)d_in[0];
  const float* phy  = (const float*)d_in[1];
  const float* Wi1  = (const float*)d_in[2];
  const float* bi1  = (const float*)d_in[3];
  const float* Wi2  = (const float*)d_in[4];
  const float* bi2  = (const float*)d_in[5];
  const float* Wo1  = (const float*)d_in[6];
  const float* bo1  = (const float*)d_in[7];
  const float* Wo2  = (const float*)d_in[8];
  const float* bo2  = (const float*)d_in[9];
  const float* We1  = (const float*)d_in[10];
  const float* be1  = (const float*)d_in[11];
  const float* We2  = (const float*)d_in[12];
  const float* be2  = (const float*)d_in[13];
  const float* Wfm  = (const float*)d_in[14];
  const float* bfm  = (const float*)d_in[15];
  const float* Wg1  = (const float*)d_in[16];
  const float* bg1  = (const float*)d_in[17];
  const float* Wg2  = (const float*)d_in[18];
  const float* bg2  = (const float*)d_in[19];
  const float* Wq   = (const float*)d_in[20];
  const float* bq   = (const float*)d_in[21];
  const float* Wk   = (const float*)d_in[22];
  const float* bk   = (const float*)d_in[23];
  const float* Wv   = (const float*)d_in[24];
  const float* bv   = (const float*)d_in[25];
  const float* Woa  = (const float*)d_in[26];
  const float* boa  = (const float*)d_in[27];
  const float* ln1s = (const float*)d_in[28];
  const float* ln1b = (const float*)d_in[29];
  const float* ln2s = (const float*)d_in[30];
  const float* ln2b = (const float*)d_in[31];
  const float* Wff1 = (const float*)d_in[32];
  const float* bff1 = (const float*)d_in[33];
  const float* Wff2 = (const float*)d_in[34];
  const float* bff2 = (const float*)d_in[35];
  const float* Wout = (const float*)d_in[36];
  const float* bout = (const float*)d_in[37];

  char* ws = (char*)d_ws;
  u16* wt = (u16*)ws;
  float* fb  = (float*)(ws + FOFF);
  float* z_t = fb + F_ZT;
  float* xf  = fb + F_XF;
  float* fq  = fb + F_Q;
  float* fk  = fb + F_K;
  float* fv  = fb + F_V;
  float* t1  = fb + F_T1;
  bf16* hb  = (bf16*)(ws + HOFF);
  bf16* xh  = hb + H_XH;
  bf16* oh  = hb + H_OH;
  bf16* ffh = hb + H_FF;

  float* out = (float*)d_out;
  float* out_pred = out;            // 480 x 160
  float* out_mu   = out + 76800;    // 480 x 64
  float* out_z    = out + 107520;   // 480 x 64

  ode_kernel<<<480, 256, 0, stream>>>(data, phy, Wi1, bi1, Wi2, bi2,
                                      Wo1, bo1, Wo2, bo2, z_t, out_z);
  cd_kernel<<<9600, 64, 0, stream>>>(data, z_t, We1, be1, We2, be2,
                                     Wfm, bfm, Wg1, bg1, Wg2, bg2,
                                     xf, xh, out_mu);

  for (int l = 0; l < 6; l++) {
    transpose_layer_kernel<<<13000, 256, 0, stream>>>(
        Wq, Wk, Wv, Woa, Wff1, Wff2, Wout, wt, l);
    // QKV (z = 0,1,2)
    gemm_bt<0><<<dim3(10, 4, 3), 256, 0, stream>>>(
        (const u16*)xh, wt + WT_Q, SLICE_DD,
        bq + l * 1280, bk + l * 1280, bv + l * 1280,
        fq, nullptr, 614400, 480, 1280, 1280);
    attn_kernel<<<384, 64, 0, stream>>>(fq, fk, fv, oh);
    gemm_bt<0><<<dim3(10, 4, 1), 256, 0, stream>>>(
        (const u16*)oh, wt + WT_O, 0,
        boa + l * 1280, boa + l * 1280, boa + l * 1280,
        t1, nullptr, 0, 480, 1280, 1280);
    ln_kernel<<<480, 256, 0, stream>>>(t1, xf, xh, ln1s + l * 1280, ln1b + l * 1280);
    gemm_bt<1><<<dim3(20, 4, 1), 256, 0, stream>>>(
        (const u16*)xh, wt + WT_F1, 0,
        bff1 + l * 2560, bff1 + l * 2560, bff1 + l * 2560,
        nullptr, ffh, 0, 480, 2560, 1280);
    gemm_bt<0><<<dim3(10, 4, 1), 256, 0, stream>>>(
        (const u16*)ffh, wt + WT_F2, 0,
        bff2 + l * 1280, bff2 + l * 1280, bff2 + l * 1280,
        t1, nullptr, 0, 480, 1280, 2560);
    ln_kernel<<<480, 256, 0, stream>>>(t1, xf, xh, ln2s + l * 1280, ln2b + l * 1280);
  }

  gemm_bt<0><<<dim3(2, 4, 1), 256, 0, stream>>>(
      (const u16*)xh, wt + WT_OUT, 0, bout, bout, bout,
      out_pred, nullptr, 0, 480, 160, 1280);
}

// Round 3
// 1493.209 us; speedup vs baseline: 1.4228x; 1.4228x over previous
//
#include <hip/hip_runtime.h>
#include <hip/hip_bf16.h>

// DS_ODE: K=3 ensemble, B=32, N=5, T=20, S=4, H=64, D=1280, DFF=2560, L=6.
// R3: ODE rewritten barrier-free (1 wave per row, weights in VGPRs, readlane
// broadcast); GEMM retiled 64x128 with register prefetch of next K-tile.

using bf16 = __hip_bfloat16;
typedef unsigned short u16;
typedef __bf16 bf16x8 __attribute__((ext_vector_type(8)));
typedef float f32x4 __attribute__((ext_vector_type(4)));

#define DEV_INLINE __device__ __forceinline__

DEV_INLINE bf16 f2bf(float v) { return __float2bfloat16(v); }
DEV_INLINE u16 f2bfu(float v) {
  bf16 h = __float2bfloat16(v);
  return *(u16*)&h;
}
DEV_INLINE float rlf(float v, int lane) {
  return __uint_as_float(__builtin_amdgcn_readlane(__float_as_uint(v), lane));
}
DEV_INLINE float ftanh(float x) {
  float ax = fminf(fabsf(x), 15.f);
  float e = __expf(-2.f * ax);
  float r = (1.f - e) * __builtin_amdgcn_rcpf(1.f + e);
  return x < 0.f ? -r : r;
}
DEV_INLINE float fsig(float x) {
  return __builtin_amdgcn_rcpf(1.f + __expf(-x));
}

// ---------------- workspace layout ----------------
constexpr size_t SLICE_DD = 1280 * 1280;
constexpr size_t SLICE_DF = 1280 * 2560;
constexpr size_t WT_Q   = 0;
constexpr size_t WT_K   = SLICE_DD;
constexpr size_t WT_V   = 2 * SLICE_DD;
constexpr size_t WT_O   = 3 * SLICE_DD;
constexpr size_t WT_F1  = 4 * SLICE_DD;
constexpr size_t WT_F2  = WT_F1 + SLICE_DF;
constexpr size_t WT_OUT = WT_F2 + SLICE_DF;
constexpr size_t WT_END = WT_OUT + 160 * 1280;
constexpr size_t FOFF   = WT_END * 2;
constexpr size_t F_ZT = 0;                        // z_t: 480*20*64
constexpr size_t F_XF = F_ZT + 614400;            // x master fp32 480*1280
constexpr size_t F_Q  = F_XF + 614400;
constexpr size_t F_K  = F_Q + 614400;
constexpr size_t F_V  = F_K + 614400;
constexpr size_t F_T1 = F_V + 614400;             // gemm out scratch 480*2560
constexpr size_t F_END = F_T1 + 1228800;
constexpr size_t HOFF = FOFF + F_END * 4;
constexpr size_t H_XH = 0;
constexpr size_t H_OH = 614400;
constexpr size_t H_FF = 1228800;

// ---------------- per-layer weight transpose + fp32->bf16 ----------------
__global__ __launch_bounds__(256) void transpose_layer_kernel(
    const float* __restrict__ Wq, const float* __restrict__ Wk,
    const float* __restrict__ Wv, const float* __restrict__ Wo,
    const float* __restrict__ Wff1, const float* __restrict__ Wff2,
    const float* __restrict__ Wout, u16* __restrict__ wt, int l) {
  int bid = blockIdx.x;
  const float* src;
  u16* dst;
  int R, C, tile;
  if (bid < 6400) {
    int mat = bid / 1600;
    tile = bid % 1600;
    src = (mat == 0 ? Wq : mat == 1 ? Wk : mat == 2 ? Wv : Wo) + (size_t)l * SLICE_DD;
    dst = wt + (size_t)mat * SLICE_DD;
    R = 1280; C = 1280;
  } else if (bid < 9600) {
    tile = bid - 6400;
    src = Wff1 + (size_t)l * SLICE_DF;
    dst = wt + WT_F1;
    R = 1280; C = 2560;
  } else if (bid < 12800) {
    tile = bid - 9600;
    src = Wff2 + (size_t)l * SLICE_DF;
    dst = wt + WT_F2;
    R = 2560; C = 1280;
  } else {
    tile = bid - 12800;
    src = Wout;
    dst = wt + WT_OUT;
    R = 1280; C = 160;
  }
  int tc = C >> 5;
  int r0 = (tile / tc) << 5, c0 = (tile % tc) << 5;
  __shared__ u16 tl[32][36];
  int t = threadIdx.x;
  int rr = t >> 3, c4 = (t & 7) << 2;
  float4 v = *(const float4*)&src[(size_t)(r0 + rr) * C + (c0 + c4)];
  tl[rr][c4 + 0] = f2bfu(v.x);
  tl[rr][c4 + 1] = f2bfu(v.y);
  tl[rr][c4 + 2] = f2bfu(v.z);
  tl[rr][c4 + 3] = f2bfu(v.w);
  __syncthreads();
  ushort4 o;
  o.x = tl[c4 + 0][rr];
  o.y = tl[c4 + 1][rr];
  o.z = tl[c4 + 2][rr];
  o.w = tl[c4 + 3][rr];
  *(ushort4*)&dst[(size_t)(c0 + rr) * R + (r0 + c4)] = o;
}

// ---------------- GEMM: C[M,N] = A[M,K] @ Bt[N,K]^T + bias ----------------
// 64x128 block tile, BK=32, 4 waves each 64x32 (4x2 16x16x32 MFMA frags).
// Register prefetch of next K-tile overlaps global latency with MFMA.
// EPI: 0 = fp32 out, 1 = relu + bf16 out.
template <int EPI>
__global__ __launch_bounds__(256) void gemm_bt(
    const u16* __restrict__ A, const u16* __restrict__ Bt, size_t btz,
    const float* __restrict__ bz0, const float* __restrict__ bz1,
    const float* __restrict__ bz2, float* __restrict__ Cf,
    bf16* __restrict__ Ch, size_t outz, int M, int N, int K) {
  const int tid = threadIdx.x;
  const int l = tid & 63;
  const int wn = tid >> 6;
  const int n0 = blockIdx.x * 128, m0 = blockIdx.y * 64;
  const int z = blockIdx.z;
  Bt += (size_t)z * btz;
  const float* bias = (z == 0) ? bz0 : (z == 1 ? bz1 : bz2);
  if (EPI == 0) Cf += (size_t)z * outz; else Ch += (size_t)z * outz;

  __shared__ u16 As[64 * 32];
  __shared__ u16 Bs[128 * 32];
  f32x4 acc[4][2] = {};

  const int oA = (tid & 3) * 8;
  int gr = m0 + (tid >> 2); if (gr >= M) gr = M - 1;
  int gn0 = n0 + (tid >> 2); if (gn0 >= N) gn0 = N - 1;
  int gn1 = n0 + 64 + (tid >> 2); if (gn1 >= N) gn1 = N - 1;
  const u16* pA  = &A[(size_t)gr * K + oA];
  const u16* pB0 = &Bt[(size_t)gn0 * K + oA];
  const u16* pB1 = &Bt[(size_t)gn1 * K + oA];

  uint4 va  = *(const uint4*)pA;
  uint4 vb0 = *(const uint4*)pB0;
  uint4 vb1 = *(const uint4*)pB1;

  for (int kt = 0; kt < K; kt += 32) {
    __syncthreads();
    *(uint4*)&As[tid * 8] = va;
    *(uint4*)&Bs[tid * 8] = vb0;
    *(uint4*)&Bs[(tid + 256) * 8] = vb1;
    __syncthreads();
    if (kt + 32 < K) {                 // prefetch next tile into regs
      va  = *(const uint4*)(pA + kt + 32);
      vb0 = *(const uint4*)(pB0 + kt + 32);
      vb1 = *(const uint4*)(pB1 + kt + 32);
    }
    bf16x8 af[4], bfr[2];
#pragma unroll
    for (int mt = 0; mt < 4; mt++)
      af[mt] = *(const bf16x8*)&As[(mt * 16 + (l & 15)) * 32 + (l >> 4) * 8];
#pragma unroll
    for (int nt = 0; nt < 2; nt++)
      bfr[nt] = *(const bf16x8*)&Bs[(wn * 32 + nt * 16 + (l & 15)) * 32 + (l >> 4) * 8];
#pragma unroll
    for (int mt = 0; mt < 4; mt++)
#pragma unroll
      for (int nt = 0; nt < 2; nt++)
        acc[mt][nt] = __builtin_amdgcn_mfma_f32_16x16x32_bf16(af[mt], bfr[nt], acc[mt][nt], 0, 0, 0);
  }

#pragma unroll
  for (int mt = 0; mt < 4; mt++)
#pragma unroll
    for (int nt = 0; nt < 2; nt++)
#pragma unroll
      for (int r = 0; r < 4; r++) {
        int row = m0 + mt * 16 + (l >> 4) * 4 + r;
        int col = n0 + wn * 32 + nt * 16 + (l & 15);
        if (row < M && col < N) {
          float v = acc[mt][nt][r] + bias[col];
          if (EPI == 1) v = fmaxf(v, 0.f);
          if (EPI == 0) Cf[(size_t)row * N + col] = v;
          else Ch[(size_t)row * N + col] = f2bf(v);
        }
      }
}

// ---------------- ODE kernel: ONE WAVE per (kb,n) row — barrier-free ------
// Wo1/Wo2 are shared (no K index): 132 weight columns live in VGPRs.
// State z replicated lane=dim; matvecs via readlane broadcast. No LDS in loop.
__global__ __launch_bounds__(64) void ode_kernel(
    const float* __restrict__ data, const float* __restrict__ phy,
    const float* __restrict__ Wi1, const float* __restrict__ bi1,
    const float* __restrict__ Wi2, const float* __restrict__ bi2,
    const float* __restrict__ Wo1, const float* __restrict__ bo1,
    const float* __restrict__ Wo2, const float* __restrict__ bo2,
    float* __restrict__ z_t, float* __restrict__ out_z) {
  const int r = blockIdx.x;          // 0..479 = kb*5+n
  const int kb = r / 5, n = r % 5;
  const int kx = kb >> 5, b = kb & 31;
  const int lane = threadIdx.x;

  __shared__ float obs[80];          // this row's data[b][n][t][s]
  obs[lane] = data[(size_t)(b * 5 + n) * 80 + lane];
  if (lane < 16) obs[64 + lane] = data[(size_t)(b * 5 + n) * 80 + 64 + lane];

  float w1[64], wx[4], w2[64];
#pragma unroll
  for (int i = 0; i < 64; i++) w1[i] = Wo1[i * 64 + lane];
#pragma unroll
  for (int s = 0; s < 4; s++) wx[s] = Wo1[(64 + s) * 64 + lane];
#pragma unroll
  for (int i = 0; i < 64; i++) w2[i] = Wo2[i * 64 + lane];
  const float bb1 = bo1[lane], bb2 = bo2[lane];

  __syncthreads();  // obs visible (single wave: compiles to waitcnt)

  // ---- z0 encoder (fused) ----
  float pin[14];
#pragma unroll
  for (int s = 0; s < 4; s++) pin[s] = obs[s];
  pin[4] = obs[0];
  pin[5] = obs[1];
#pragma unroll
  for (int s = 0; s < 8; s++) pin[6 + s] = phy[b * 8 + s];

  float h1 = bi1[kx * 64 + lane];
#pragma unroll
  for (int f = 0; f < 14; f++)
    h1 = fmaf(pin[f], Wi1[(kx * 14 + f) * 64 + lane], h1);
  h1 = ftanh(h1);

  float zz = bi2[kx * 64 + lane];
#pragma unroll
  for (int i = 0; i < 64; i++)
    zz = fmaf(rlf(h1, i), Wi2[(size_t)(kx * 64 + i) * 64 + lane], zz);

  z_t[(size_t)r * 1280 + lane] = zz;  // tt = 0

  auto feval = [&](float y, const float* o4) -> float {
    float a0 = 0.f, a1 = 0.f, a2 = 0.f, a3 = 0.f;
#pragma unroll
    for (int i = 0; i < 64; i += 4) {
      a0 = fmaf(rlf(y, i + 0), w1[i + 0], a0);
      a1 = fmaf(rlf(y, i + 1), w1[i + 1], a1);
      a2 = fmaf(rlf(y, i + 2), w1[i + 2], a2);
      a3 = fmaf(rlf(y, i + 3), w1[i + 3], a3);
    }
    float hh = ((a0 + a1) + (a2 + a3)) + bb1;
#pragma unroll
    for (int s = 0; s < 4; s++) hh = fmaf(o4[s], wx[s], hh);
    hh = ftanh(hh);
    float q0 = 0.f, q1 = 0.f, q2 = 0.f, q3 = 0.f;
#pragma unroll
    for (int i = 0; i < 64; i += 4) {
      q0 = fmaf(rlf(hh, i + 0), w2[i + 0], q0);
      q1 = fmaf(rlf(hh, i + 1), w2[i + 1], q1);
      q2 = fmaf(rlf(hh, i + 2), w2[i + 2], q2);
      q3 = fmaf(rlf(hh, i + 3), w2[i + 3], q3);
    }
    return ((q0 + q1) + (q2 + q3)) + bb2;
  };

  auto interp4 = [&](float t, float* o) {
    int i0 = (int)t;                   // t >= 0
    if (i0 > 18) i0 = 18;
    float fr = t - (float)i0;
#pragma unroll
    for (int s = 0; s < 4; s++) {      // same-addr LDS reads = broadcast
      float a = obs[i0 * 4 + s], c = obs[i0 * 4 + 4 + s];
      o[s] = fmaf(fr, c - a, a);
    }
  };

  for (int j = 0; j < 190; j++) {
    float t = (float)j * 0.1f;
    float oA[4], oB[4], oC[4];
    interp4(t, oA);
    interp4(t + 0.05f, oB);
    interp4(t + 0.1f, oC);
    float k1 = feval(zz, oA);
    float k2 = feval(fmaf(0.05f, k1, zz), oB);
    float k3 = feval(fmaf(0.05f, k2, zz), oB);
    float k4 = feval(fmaf(0.1f, k3, zz), oC);
    zz = fmaf(0.1f / 6.f, k1 + 2.f * k2 + 2.f * k3 + k4, zz);
    if (((j + 1) % 10) == 0) {
      int tt = (j + 1) / 10;
      z_t[(size_t)(r * 20 + tt) * 64 + lane] = zz;
      if (tt == 19) out_z[(size_t)r * 64 + lane] = zz;
    }
  }
}

// ---------------- mu / proj / gate / x-build: one wave per (kb,n,t) -------
__global__ __launch_bounds__(64) void cd_kernel(
    const float* __restrict__ data, const float* __restrict__ z_t,
    const float* __restrict__ We1, const float* __restrict__ be1,
    const float* __restrict__ We2, const float* __restrict__ be2,
    const float* __restrict__ Wfm, const float* __restrict__ bfm,
    const float* __restrict__ Wg1, const float* __restrict__ bg1,
    const float* __restrict__ Wg2, const float* __restrict__ bg2,
    float* __restrict__ xf, bf16* __restrict__ xh, float* __restrict__ out_mu) {
  const int rt = blockIdx.x;  // (kb*5+n)*20 + t
  const int lane = threadIdx.x;
  const int kb = rt / 100;
  const int rem = rt % 100;
  const int n = rem / 20, t = rem % 20;
  const int b = kb & 31, kx = kb >> 5;

  float obs4[4];
#pragma unroll
  for (int s = 0; s < 4; s++)
    obs4[s] = data[(size_t)((b * 5 + n) * 20 + t) * 4 + s];

  float mh = be1[lane];
#pragma unroll
  for (int s = 0; s < 4; s++) mh = fmaf(obs4[s], We1[s * 64 + lane], mh);
  mh = fmaxf(mh, 0.f);

  float mu = be2[lane];
#pragma unroll 16
  for (int h = 0; h < 64; h++) mu = fmaf(rlf(mh, h), We2[h * 64 + lane], mu);

  if (t == 19) out_mu[(size_t)(kb * 5 + n) * 64 + lane] = mu;

  float zv = z_t[(size_t)rt * 64 + lane];

  float pj = bfm[lane];
#pragma unroll 16
  for (int h = 0; h < 64; h++) pj = fmaf(rlf(zv, h), Wfm[h * 64 + lane], pj);
#pragma unroll 16
  for (int h = 0; h < 64; h++) pj = fmaf(rlf(mu, h), Wfm[(64 + h) * 64 + lane], pj);

  float gh = bg1[kx * 64 + lane];
#pragma unroll 16
  for (int h = 0; h < 64; h++)
    gh = fmaf(rlf(pj, h), Wg1[(size_t)(kx * 64 + h) * 64 + lane], gh);
  gh = ftanh(gh);

  float gt = bg2[kx * 64 + lane];
#pragma unroll 16
  for (int h = 0; h < 64; h++)
    gt = fmaf(rlf(gh, h), Wg2[(size_t)(kx * 64 + h) * 64 + lane], gt);
  gt = fsig(gt);

  float xv = pj * gt;
  size_t xo = (size_t)(kb * 5 + n) * 1280 + t * 64 + lane;
  xf[xo] = xv;
  xh[xo] = f2bf(xv);
}

// ---------------- attention: one wave per (kb, head) ----------------------
__global__ __launch_bounds__(64) void attn_kernel(
    const float* __restrict__ q, const float* __restrict__ k,
    const float* __restrict__ v, bf16* __restrict__ oh) {
  const int kb = blockIdx.x >> 2, h = blockIdx.x & 3;
  const int lane = threadIdx.x;
  const size_t base = (size_t)(kb * 5) * 1280 + h * 320 + lane;
  float qv[5][5], kv[5][5], vv[5][5];
#pragma unroll
  for (int i = 0; i < 5; i++)
#pragma unroll
    for (int c = 0; c < 5; c++) {
      size_t off = base + (size_t)i * 1280 + c * 64;
      qv[i][c] = q[off];
      kv[i][c] = k[off];
      vv[i][c] = v[off];
    }
  float s[5][5];
#pragma unroll
  for (int i = 0; i < 5; i++)
#pragma unroll
    for (int j = 0; j < 5; j++) {
      float a = 0.f;
#pragma unroll
      for (int c = 0; c < 5; c++) a = fmaf(qv[i][c], kv[j][c], a);
#pragma unroll
      for (int m = 1; m < 64; m <<= 1) a += __shfl_xor(a, m, 64);
      s[i][j] = a * 0.055901699437494745f;  // 1/sqrt(320)
    }
#pragma unroll
  for (int i = 0; i < 5; i++) {
    float mx = s[i][0];
#pragma unroll
    for (int j = 1; j < 5; j++) mx = fmaxf(mx, s[i][j]);
    float sum = 0.f;
#pragma unroll
    for (int j = 0; j < 5; j++) {
      s[i][j] = __expf(s[i][j] - mx);
      sum += s[i][j];
    }
    float inv = __builtin_amdgcn_rcpf(sum);
#pragma unroll
    for (int j = 0; j < 5; j++) s[i][j] *= inv;
  }
#pragma unroll
  for (int i = 0; i < 5; i++)
#pragma unroll
    for (int c = 0; c < 5; c++) {
      float a = 0.f;
#pragma unroll
      for (int j = 0; j < 5; j++) a = fmaf(s[i][j], vv[j][c], a);
      oh[base + (size_t)i * 1280 + c * 64] = f2bf(a);
    }
}

// ---------------- residual + layernorm: one block per row -----------------
__global__ __launch_bounds__(256) void ln_kernel(
    const float* __restrict__ g, float* __restrict__ xf, bf16* __restrict__ xh,
    const float* __restrict__ sc, const float* __restrict__ bi) {
  const int row = blockIdx.x, tid = threadIdx.x;
  const size_t base = (size_t)row * 1280;
  float v[5], s1 = 0.f, s2 = 0.f;
#pragma unroll
  for (int i = 0; i < 5; i++) {
    int c = tid + i * 256;
    float x = xf[base + c] + g[base + c];
    v[i] = x;
    s1 += x;
    s2 = fmaf(x, x, s2);
  }
#pragma unroll
  for (int m = 1; m < 64; m <<= 1) {
    s1 += __shfl_xor(s1, m, 64);
    s2 += __shfl_xor(s2, m, 64);
  }
  __shared__ float r1[4], r2[4];
  const int wv = tid >> 6;
  if ((tid & 63) == 0) { r1[wv] = s1; r2[wv] = s2; }
  __syncthreads();
  s1 = r1[0] + r1[1] + r1[2] + r1[3];
  s2 = r2[0] + r2[1] + r2[2] + r2[3];
  const float mean = s1 * (1.f / 1280.f);
  float var = s2 * (1.f / 1280.f) - mean * mean;
  var = fmaxf(var, 0.f);
  const float rs = rsqrtf(var + 1e-5f);
#pragma unroll
  for (int i = 0; i < 5; i++) {
    int c = tid + i * 256;
    float y = (v[i] - mean) * rs * sc[c] + bi[c];
    xf[base + c] = y;
    xh[base + c] = f2bf(y);
  }
}

// ---------------- host launcher -------------------------------------------
extern "C" void kernel_launch(void* const* d_in, const int* in_sizes, int n_in,
                              void* d_out, int out_size, void* d_ws, size_t ws_size,
                              hipStream_t stream) {
  const float* data = (const float*)d_in[0];
  const float* phy  = (const float*)d_in[1];
  const float* Wi1  = (const float*)d_in[2];
  const float* bi1  = (const float*)d_in[3];
  const float* Wi2  = (const float*)d_in[4];
  const float* bi2  = (const float*)d_in[5];
  const float* Wo1  = (const float*)d_in[6];
  const float* bo1  = (const float*)d_in[7];
  const float* Wo2  = (const float*)d_in[8];
  const float* bo2  = (const float*)d_in[9];
  const float* We1  = (const float*)d_in[10];
  const float* be1  = (const float*)d_in[11];
  const float* We2  = (const float*)d_in[12];
  const float* be2  = (const float*)d_in[13];
  const float* Wfm  = (const float*)d_in[14];
  const float* bfm  = (const float*)d_in[15];
  const float* Wg1  = (const float*)d_in[16];
  const float* bg1  = (const float*)d_in[17];
  const float* Wg2  = (const float*)d_in[18];
  const float* bg2  = (const float*)d_in[19];
  const float* Wq   = (const float*)d_in[20];
  const float* bq   = (const float*)d_in[21];
  const float* Wk   = (const float*)d_in[22];
  const float* bk   = (const float*)d_in[23];
  const float* Wv   = (const float*)d_in[24];
  const float* bv   = (const float*)d_in[25];
  const float* Woa  = (const float*)d_in[26];
  const float* boa  = (const float*)d_in[27];
  const float* ln1s = (const float*)d_in[28];
  const float* ln1b = (const float*)d_in[29];
  const float* ln2s = (const float*)d_in[30];
  const float* ln2b = (const float*)d_in[31];
  const float* Wff1 = (const float*)d_in[32];
  const float* bff1 = (const float*)d_in[33];
  const float* Wff2 = (const float*)d_in[34];
  const float* bff2 = (const float*)d_in[35];
  const float* Wout = (const float*)d_in[36];
  const float* bout = (const float*)d_in[37];

  char* ws = (char*)d_ws;
  u16* wt = (u16*)ws;
  float* fb  = (float*)(ws + FOFF);
  float* z_t = fb + F_ZT;
  float* xf  = fb + F_XF;
  float* fq  = fb + F_Q;
  float* fk  = fb + F_K;
  float* fv  = fb + F_V;
  float* t1  = fb + F_T1;
  bf16* hb  = (bf16*)(ws + HOFF);
  bf16* xh  = hb + H_XH;
  bf16* oh  = hb + H_OH;
  bf16* ffh = hb + H_FF;

  float* out = (float*)d_out;
  float* out_pred = out;            // 480 x 160
  float* out_mu   = out + 76800;    // 480 x 64
  float* out_z    = out + 107520;   // 480 x 64

  ode_kernel<<<480, 64, 0, stream>>>(data, phy, Wi1, bi1, Wi2, bi2,
                                     Wo1, bo1, Wo2, bo2, z_t, out_z);
  cd_kernel<<<9600, 64, 0, stream>>>(data, z_t, We1, be1, We2, be2,
                                     Wfm, bfm, Wg1, bg1, Wg2, bg2,
                                     xf, xh, out_mu);

  for (int l = 0; l < 6; l++) {
    transpose_layer_kernel<<<13000, 256, 0, stream>>>(
        Wq, Wk, Wv, Woa, Wff1, Wff2, Wout, wt, l);
    // QKV (z = 0,1,2): 240 blocks
    gemm_bt<0><<<dim3(10, 8, 3), 256, 0, stream>>>(
        (const u16*)xh, wt + WT_Q, SLICE_DD,
        bq + l * 1280, bk + l * 1280, bv + l * 1280,
        fq, nullptr, 614400, 480, 1280, 1280);
    attn_kernel<<<384, 64, 0, stream>>>(fq, fk, fv, oh);
    gemm_bt<0><<<dim3(10, 8, 1), 256, 0, stream>>>(
        (const u16*)oh, wt + WT_O, 0,
        boa + l * 1280, boa + l * 1280, boa + l * 1280,
        t1, nullptr, 0, 480, 1280, 1280);
    ln_kernel<<<480, 256, 0, stream>>>(t1, xf, xh, ln1s + l * 1280, ln1b + l * 1280);
    gemm_bt<1><<<dim3(20, 8, 1), 256, 0, stream>>>(
        (const u16*)xh, wt + WT_F1, 0,
        bff1 + l * 2560, bff1 + l * 2560, bff1 + l * 2560,
        nullptr, ffh, 0, 480, 2560, 1280);
    gemm_bt<0><<<dim3(10, 8, 1), 256, 0, stream>>>(
        (const u16*)ffh, wt + WT_F2, 0,
        bff2 + l * 1280, bff2 + l * 1280, bff2 + l * 1280,
        t1, nullptr, 0, 480, 1280, 2560);
    ln_kernel<<<480, 256, 0, stream>>>(t1, xf, xh, ln2s + l * 1280, ln2b + l * 1280);
  }

  gemm_bt<0><<<dim3(2, 8, 1), 256, 0, stream>>>(
      (const u16*)xh, wt + WT_OUT, 0, bout, bout, bout,
      out_pred, nullptr, 0, 480, 160, 1280);
}

// Round 4
// 1325.442 us; speedup vs baseline: 1.6028x; 1.1266x over previous
//
#include <hip/hip_runtime.h>
#include <hip/hip_bf16.h>

// DS_ODE: K=3 ensemble, B=32, N=5, T=20, S=4, H=64, D=1280, DFF=2560, L=6.
// R4: (1) ode __launch_bounds__(64,1) to kill VGPR spills (R3 had VGPR=100 <
// 170 needed -> scratch spills, VALUBusy 37%); (2) GEMM BK=64 + double-buffered
// LDS, 1 barrier/iter, 2-tile-deep register prefetch.

using bf16 = __hip_bfloat16;
typedef unsigned short u16;
typedef __bf16 bf16x8 __attribute__((ext_vector_type(8)));
typedef float f32x4 __attribute__((ext_vector_type(4)));

#define DEV_INLINE __device__ __forceinline__

DEV_INLINE bf16 f2bf(float v) { return __float2bfloat16(v); }
DEV_INLINE u16 f2bfu(float v) {
  bf16 h = __float2bfloat16(v);
  return *(u16*)&h;
}
DEV_INLINE float rlf(float v, int lane) {
  return __uint_as_float(__builtin_amdgcn_readlane(__float_as_uint(v), lane));
}
DEV_INLINE float ftanh(float x) {
  float ax = fminf(fabsf(x), 15.f);
  float e = __expf(-2.f * ax);
  float r = (1.f - e) * __builtin_amdgcn_rcpf(1.f + e);
  return x < 0.f ? -r : r;
}
DEV_INLINE float fsig(float x) {
  return __builtin_amdgcn_rcpf(1.f + __expf(-x));
}

// ---------------- workspace layout ----------------
constexpr size_t SLICE_DD = 1280 * 1280;
constexpr size_t SLICE_DF = 1280 * 2560;
constexpr size_t WT_Q   = 0;
constexpr size_t WT_K   = SLICE_DD;
constexpr size_t WT_V   = 2 * SLICE_DD;
constexpr size_t WT_O   = 3 * SLICE_DD;
constexpr size_t WT_F1  = 4 * SLICE_DD;
constexpr size_t WT_F2  = WT_F1 + SLICE_DF;
constexpr size_t WT_OUT = WT_F2 + SLICE_DF;
constexpr size_t WT_END = WT_OUT + 160 * 1280;
constexpr size_t FOFF   = WT_END * 2;
constexpr size_t F_ZT = 0;                        // z_t: 480*20*64
constexpr size_t F_XF = F_ZT + 614400;            // x master fp32 480*1280
constexpr size_t F_Q  = F_XF + 614400;
constexpr size_t F_K  = F_Q + 614400;
constexpr size_t F_V  = F_K + 614400;
constexpr size_t F_T1 = F_V + 614400;             // gemm out scratch 480*2560
constexpr size_t F_END = F_T1 + 1228800;
constexpr size_t HOFF = FOFF + F_END * 4;
constexpr size_t H_XH = 0;
constexpr size_t H_OH = 614400;
constexpr size_t H_FF = 1228800;

// ---------------- per-layer weight transpose + fp32->bf16 ----------------
__global__ __launch_bounds__(256) void transpose_layer_kernel(
    const float* __restrict__ Wq, const float* __restrict__ Wk,
    const float* __restrict__ Wv, const float* __restrict__ Wo,
    const float* __restrict__ Wff1, const float* __restrict__ Wff2,
    const float* __restrict__ Wout, u16* __restrict__ wt, int l) {
  int bid = blockIdx.x;
  const float* src;
  u16* dst;
  int R, C, tile;
  if (bid < 6400) {
    int mat = bid / 1600;
    tile = bid % 1600;
    src = (mat == 0 ? Wq : mat == 1 ? Wk : mat == 2 ? Wv : Wo) + (size_t)l * SLICE_DD;
    dst = wt + (size_t)mat * SLICE_DD;
    R = 1280; C = 1280;
  } else if (bid < 9600) {
    tile = bid - 6400;
    src = Wff1 + (size_t)l * SLICE_DF;
    dst = wt + WT_F1;
    R = 1280; C = 2560;
  } else if (bid < 12800) {
    tile = bid - 9600;
    src = Wff2 + (size_t)l * SLICE_DF;
    dst = wt + WT_F2;
    R = 2560; C = 1280;
  } else {
    tile = bid - 12800;
    src = Wout;
    dst = wt + WT_OUT;
    R = 1280; C = 160;
  }
  int tc = C >> 5;
  int r0 = (tile / tc) << 5, c0 = (tile % tc) << 5;
  __shared__ u16 tl[32][36];
  int t = threadIdx.x;
  int rr = t >> 3, c4 = (t & 7) << 2;
  float4 v = *(const float4*)&src[(size_t)(r0 + rr) * C + (c0 + c4)];
  tl[rr][c4 + 0] = f2bfu(v.x);
  tl[rr][c4 + 1] = f2bfu(v.y);
  tl[rr][c4 + 2] = f2bfu(v.z);
  tl[rr][c4 + 3] = f2bfu(v.w);
  __syncthreads();
  ushort4 o;
  o.x = tl[c4 + 0][rr];
  o.y = tl[c4 + 1][rr];
  o.z = tl[c4 + 2][rr];
  o.w = tl[c4 + 3][rr];
  *(ushort4*)&dst[(size_t)(c0 + rr) * R + (r0 + c4)] = o;
}

// ---------------- GEMM: C[M,N] = A[M,K] @ Bt[N,K]^T + bias ----------------
// 64x128 tile, BK=64, double-buffered LDS ([buf][ks][row*32+k] keeps the
// conflict-free fragment pattern), one barrier/iter, prefetch 2 tiles deep.
// EPI: 0 = fp32 out, 1 = relu + bf16 out.
template <int EPI>
__global__ __launch_bounds__(256) void gemm_bt(
    const u16* __restrict__ A, const u16* __restrict__ Bt, size_t btz,
    const float* __restrict__ bz0, const float* __restrict__ bz1,
    const float* __restrict__ bz2, float* __restrict__ Cf,
    bf16* __restrict__ Ch, size_t outz, int M, int N, int K) {
  const int tid = threadIdx.x;
  const int l = tid & 63;
  const int wn = tid >> 6;
  const int n0 = blockIdx.x * 128, m0 = blockIdx.y * 64;
  const int z = blockIdx.z;
  Bt += (size_t)z * btz;
  const float* bias = (z == 0) ? bz0 : (z == 1 ? bz1 : bz2);
  if (EPI == 0) Cf += (size_t)z * outz; else Ch += (size_t)z * outz;

  __shared__ u16 As[2][2][64 * 32];    // [buf][ks][row*32 + k]
  __shared__ u16 Bs[2][2][128 * 32];
  f32x4 acc[4][2] = {};

  const int lrow = tid >> 2;           // 0..63
  const int loct = (tid & 3) * 8;      // k offset within a 32-k subtile
  int ar  = m0 + lrow;      if (ar  >= M) ar  = M - 1;
  int br0 = n0 + lrow;      if (br0 >= N) br0 = N - 1;
  int br1 = n0 + 64 + lrow; if (br1 >= N) br1 = N - 1;
  const u16* pA  = &A [(size_t)ar  * K + loct];
  const u16* pB0 = &Bt[(size_t)br0 * K + loct];
  const u16* pB1 = &Bt[(size_t)br1 * K + loct];

  uint4 a0  = *(const uint4*)(pA);
  uint4 a1  = *(const uint4*)(pA + 32);
  uint4 b00 = *(const uint4*)(pB0);
  uint4 b01 = *(const uint4*)(pB0 + 32);
  uint4 b10 = *(const uint4*)(pB1);
  uint4 b11 = *(const uint4*)(pB1 + 32);

  // stage tile 0 -> buf 0 (flat contiguous per lane: no write conflicts)
  *(uint4*)&As[0][0][tid * 8] = a0;
  *(uint4*)&As[0][1][tid * 8] = a1;
  *(uint4*)&Bs[0][0][tid * 8] = b00;
  *(uint4*)&Bs[0][1][tid * 8] = b01;
  *(uint4*)&Bs[0][0][(tid + 256) * 8] = b10;
  *(uint4*)&Bs[0][1][(tid + 256) * 8] = b11;

  const int nT = K >> 6;
  if (nT > 1) {                        // prefetch tile 1 into regs
    a0  = *(const uint4*)(pA  + 64);
    a1  = *(const uint4*)(pA  + 96);
    b00 = *(const uint4*)(pB0 + 64);
    b01 = *(const uint4*)(pB0 + 96);
    b10 = *(const uint4*)(pB1 + 64);
    b11 = *(const uint4*)(pB1 + 96);
  }
  __syncthreads();

  for (int it = 0; it < nT; it++) {
    const int p = it & 1;
    bf16x8 af[2][4], bfr[2][2];
#pragma unroll
    for (int ks = 0; ks < 2; ks++) {
#pragma unroll
      for (int mt = 0; mt < 4; mt++)
        af[ks][mt] = *(const bf16x8*)&As[p][ks][(mt * 16 + (l & 15)) * 32 + (l >> 4) * 8];
#pragma unroll
      for (int nt = 0; nt < 2; nt++)
        bfr[ks][nt] = *(const bf16x8*)&Bs[p][ks][(wn * 32 + nt * 16 + (l & 15)) * 32 + (l >> 4) * 8];
    }
    if (it + 1 < nT) {                 // stage prefetched tile -> other buf
      *(uint4*)&As[1 - p][0][tid * 8] = a0;
      *(uint4*)&As[1 - p][1][tid * 8] = a1;
      *(uint4*)&Bs[1 - p][0][tid * 8] = b00;
      *(uint4*)&Bs[1 - p][1][tid * 8] = b01;
      *(uint4*)&Bs[1 - p][0][(tid + 256) * 8] = b10;
      *(uint4*)&Bs[1 - p][1][(tid + 256) * 8] = b11;
      if (it + 2 < nT) {               // prefetch tile it+2 into regs
        const int off = (it + 2) * 64;
        a0  = *(const uint4*)(pA  + off);
        a1  = *(const uint4*)(pA  + off + 32);
        b00 = *(const uint4*)(pB0 + off);
        b01 = *(const uint4*)(pB0 + off + 32);
        b10 = *(const uint4*)(pB1 + off);
        b11 = *(const uint4*)(pB1 + off + 32);
      }
    }
#pragma unroll
    for (int ks = 0; ks < 2; ks++)
#pragma unroll
      for (int mt = 0; mt < 4; mt++)
#pragma unroll
        for (int nt = 0; nt < 2; nt++)
          acc[mt][nt] = __builtin_amdgcn_mfma_f32_16x16x32_bf16(af[ks][mt], bfr[ks][nt], acc[mt][nt], 0, 0, 0);
    __syncthreads();
  }

#pragma unroll
  for (int mt = 0; mt < 4; mt++)
#pragma unroll
    for (int nt = 0; nt < 2; nt++)
#pragma unroll
      for (int r = 0; r < 4; r++) {
        int row = m0 + mt * 16 + (l >> 4) * 4 + r;
        int col = n0 + wn * 32 + nt * 16 + (l & 15);
        if (row < M && col < N) {
          float v = acc[mt][nt][r] + bias[col];
          if (EPI == 1) v = fmaxf(v, 0.f);
          if (EPI == 0) Cf[(size_t)row * N + col] = v;
          else Ch[(size_t)row * N + col] = f2bf(v);
        }
      }
}

// ---------------- ODE kernel: ONE WAVE per (kb,n) row — barrier-free ------
// (64,1): min 1 wave/EU -> full 512-VGPR budget; weights stay in registers.
__global__ __launch_bounds__(64, 1) void ode_kernel(
    const float* __restrict__ data, const float* __restrict__ phy,
    const float* __restrict__ Wi1, const float* __restrict__ bi1,
    const float* __restrict__ Wi2, const float* __restrict__ bi2,
    const float* __restrict__ Wo1, const float* __restrict__ bo1,
    const float* __restrict__ Wo2, const float* __restrict__ bo2,
    float* __restrict__ z_t, float* __restrict__ out_z) {
  const int r = blockIdx.x;          // 0..479 = kb*5+n
  const int kb = r / 5, n = r % 5;
  const int kx = kb >> 5, b = kb & 31;
  const int lane = threadIdx.x;

  __shared__ float obs[80];          // this row's data[b][n][t][s]
  obs[lane] = data[(size_t)(b * 5 + n) * 80 + lane];
  if (lane < 16) obs[64 + lane] = data[(size_t)(b * 5 + n) * 80 + 64 + lane];

  float w1[64], wx[4], w2[64];
#pragma unroll
  for (int i = 0; i < 64; i++) w1[i] = Wo1[i * 64 + lane];
#pragma unroll
  for (int s = 0; s < 4; s++) wx[s] = Wo1[(64 + s) * 64 + lane];
#pragma unroll
  for (int i = 0; i < 64; i++) w2[i] = Wo2[i * 64 + lane];
  const float bb1 = bo1[lane], bb2 = bo2[lane];

  __syncthreads();  // obs visible

  // ---- z0 encoder (fused) ----
  float pin[14];
#pragma unroll
  for (int s = 0; s < 4; s++) pin[s] = obs[s];
  pin[4] = obs[0];
  pin[5] = obs[1];
#pragma unroll
  for (int s = 0; s < 8; s++) pin[6 + s] = phy[b * 8 + s];

  float h1 = bi1[kx * 64 + lane];
#pragma unroll
  for (int f = 0; f < 14; f++)
    h1 = fmaf(pin[f], Wi1[(kx * 14 + f) * 64 + lane], h1);
  h1 = ftanh(h1);

  float zz = bi2[kx * 64 + lane];
#pragma unroll
  for (int i = 0; i < 64; i++)
    zz = fmaf(rlf(h1, i), Wi2[(size_t)(kx * 64 + i) * 64 + lane], zz);

  z_t[(size_t)r * 1280 + lane] = zz;  // tt = 0

  auto feval = [&](float y, const float* o4) -> float {
    float a0 = 0.f, a1 = 0.f, a2 = 0.f, a3 = 0.f;
#pragma unroll
    for (int i = 0; i < 64; i += 4) {
      a0 = fmaf(rlf(y, i + 0), w1[i + 0], a0);
      a1 = fmaf(rlf(y, i + 1), w1[i + 1], a1);
      a2 = fmaf(rlf(y, i + 2), w1[i + 2], a2);
      a3 = fmaf(rlf(y, i + 3), w1[i + 3], a3);
    }
    float hh = ((a0 + a1) + (a2 + a3)) + bb1;
#pragma unroll
    for (int s = 0; s < 4; s++) hh = fmaf(o4[s], wx[s], hh);
    hh = ftanh(hh);
    float q0 = 0.f, q1 = 0.f, q2 = 0.f, q3 = 0.f;
#pragma unroll
    for (int i = 0; i < 64; i += 4) {
      q0 = fmaf(rlf(hh, i + 0), w2[i + 0], q0);
      q1 = fmaf(rlf(hh, i + 1), w2[i + 1], q1);
      q2 = fmaf(rlf(hh, i + 2), w2[i + 2], q2);
      q3 = fmaf(rlf(hh, i + 3), w2[i + 3], q3);
    }
    return ((q0 + q1) + (q2 + q3)) + bb2;
  };

  auto interp4 = [&](float t, float* o) {
    int i0 = (int)t;                   // t >= 0
    if (i0 > 18) i0 = 18;
    float fr = t - (float)i0;
#pragma unroll
    for (int s = 0; s < 4; s++) {      // same-addr LDS reads = broadcast
      float a = obs[i0 * 4 + s], c = obs[i0 * 4 + 4 + s];
      o[s] = fmaf(fr, c - a, a);
    }
  };

  for (int j = 0; j < 190; j++) {
    float t = (float)j * 0.1f;
    float oA[4], oB[4], oC[4];
    interp4(t, oA);
    interp4(t + 0.05f, oB);
    interp4(t + 0.1f, oC);
    float k1 = feval(zz, oA);
    float k2 = feval(fmaf(0.05f, k1, zz), oB);
    float k3 = feval(fmaf(0.05f, k2, zz), oB);
    float k4 = feval(fmaf(0.1f, k3, zz), oC);
    zz = fmaf(0.1f / 6.f, k1 + 2.f * k2 + 2.f * k3 + k4, zz);
    if (((j + 1) % 10) == 0) {
      int tt = (j + 1) / 10;
      z_t[(size_t)(r * 20 + tt) * 64 + lane] = zz;
      if (tt == 19) out_z[(size_t)r * 64 + lane] = zz;
    }
  }
}

// ---------------- mu / proj / gate / x-build: one wave per (kb,n,t) -------
__global__ __launch_bounds__(64) void cd_kernel(
    const float* __restrict__ data, const float* __restrict__ z_t,
    const float* __restrict__ We1, const float* __restrict__ be1,
    const float* __restrict__ We2, const float* __restrict__ be2,
    const float* __restrict__ Wfm, const float* __restrict__ bfm,
    const float* __restrict__ Wg1, const float* __restrict__ bg1,
    const float* __restrict__ Wg2, const float* __restrict__ bg2,
    float* __restrict__ xf, bf16* __restrict__ xh, float* __restrict__ out_mu) {
  const int rt = blockIdx.x;  // (kb*5+n)*20 + t
  const int lane = threadIdx.x;
  const int kb = rt / 100;
  const int rem = rt % 100;
  const int n = rem / 20, t = rem % 20;
  const int b = kb & 31, kx = kb >> 5;

  float obs4[4];
#pragma unroll
  for (int s = 0; s < 4; s++)
    obs4[s] = data[(size_t)((b * 5 + n) * 20 + t) * 4 + s];

  float mh = be1[lane];
#pragma unroll
  for (int s = 0; s < 4; s++) mh = fmaf(obs4[s], We1[s * 64 + lane], mh);
  mh = fmaxf(mh, 0.f);

  float mu = be2[lane];
#pragma unroll 16
  for (int h = 0; h < 64; h++) mu = fmaf(rlf(mh, h), We2[h * 64 + lane], mu);

  if (t == 19) out_mu[(size_t)(kb * 5 + n) * 64 + lane] = mu;

  float zv = z_t[(size_t)rt * 64 + lane];

  float pj = bfm[lane];
#pragma unroll 16
  for (int h = 0; h < 64; h++) pj = fmaf(rlf(zv, h), Wfm[h * 64 + lane], pj);
#pragma unroll 16
  for (int h = 0; h < 64; h++) pj = fmaf(rlf(mu, h), Wfm[(64 + h) * 64 + lane], pj);

  float gh = bg1[kx * 64 + lane];
#pragma unroll 16
  for (int h = 0; h < 64; h++)
    gh = fmaf(rlf(pj, h), Wg1[(size_t)(kx * 64 + h) * 64 + lane], gh);
  gh = ftanh(gh);

  float gt = bg2[kx * 64 + lane];
#pragma unroll 16
  for (int h = 0; h < 64; h++)
    gt = fmaf(rlf(gh, h), Wg2[(size_t)(kx * 64 + h) * 64 + lane], gt);
  gt = fsig(gt);

  float xv = pj * gt;
  size_t xo = (size_t)(kb * 5 + n) * 1280 + t * 64 + lane;
  xf[xo] = xv;
  xh[xo] = f2bf(xv);
}

// ---------------- attention: one wave per (kb, head) ----------------------
__global__ __launch_bounds__(64) void attn_kernel(
    const float* __restrict__ q, const float* __restrict__ k,
    const float* __restrict__ v, bf16* __restrict__ oh) {
  const int kb = blockIdx.x >> 2, h = blockIdx.x & 3;
  const int lane = threadIdx.x;
  const size_t base = (size_t)(kb * 5) * 1280 + h * 320 + lane;
  float qv[5][5], kv[5][5], vv[5][5];
#pragma unroll
  for (int i = 0; i < 5; i++)
#pragma unroll
    for (int c = 0; c < 5; c++) {
      size_t off = base + (size_t)i * 1280 + c * 64;
      qv[i][c] = q[off];
      kv[i][c] = k[off];
      vv[i][c] = v[off];
    }
  float s[5][5];
#pragma unroll
  for (int i = 0; i < 5; i++)
#pragma unroll
    for (int j = 0; j < 5; j++) {
      float a = 0.f;
#pragma unroll
      for (int c = 0; c < 5; c++) a = fmaf(qv[i][c], kv[j][c], a);
#pragma unroll
      for (int m = 1; m < 64; m <<= 1) a += __shfl_xor(a, m, 64);
      s[i][j] = a * 0.055901699437494745f;  // 1/sqrt(320)
    }
#pragma unroll
  for (int i = 0; i < 5; i++) {
    float mx = s[i][0];
#pragma unroll
    for (int j = 1; j < 5; j++) mx = fmaxf(mx, s[i][j]);
    float sum = 0.f;
#pragma unroll
    for (int j = 0; j < 5; j++) {
      s[i][j] = __expf(s[i][j] - mx);
      sum += s[i][j];
    }
    float inv = __builtin_amdgcn_rcpf(sum);
#pragma unroll
    for (int j = 0; j < 5; j++) s[i][j] *= inv;
  }
#pragma unroll
  for (int i = 0; i < 5; i++)
#pragma unroll
    for (int c = 0; c < 5; c++) {
      float a = 0.f;
#pragma unroll
      for (int j = 0; j < 5; j++) a = fmaf(s[i][j], vv[j][c], a);
      oh[base + (size_t)i * 1280 + c * 64] = f2bf(a);
    }
}

// ---------------- residual + layernorm: one block per row -----------------
__global__ __launch_bounds__(256) void ln_kernel(
    const float* __restrict__ g, float* __restrict__ xf, bf16* __restrict__ xh,
    const float* __restrict__ sc, const float* __restrict__ bi) {
  const int row = blockIdx.x, tid = threadIdx.x;
  const size_t base = (size_t)row * 1280;
  float v[5], s1 = 0.f, s2 = 0.f;
#pragma unroll
  for (int i = 0; i < 5; i++) {
    int c = tid + i * 256;
    float x = xf[base + c] + g[base + c];
    v[i] = x;
    s1 += x;
    s2 = fmaf(x, x, s2);
  }
#pragma unroll
  for (int m = 1; m < 64; m <<= 1) {
    s1 += __shfl_xor(s1, m, 64);
    s2 += __shfl_xor(s2, m, 64);
  }
  __shared__ float r1[4], r2[4];
  const int wv = tid >> 6;
  if ((tid & 63) == 0) { r1[wv] = s1; r2[wv] = s2; }
  __syncthreads();
  s1 = r1[0] + r1[1] + r1[2] + r1[3];
  s2 = r2[0] + r2[1] + r2[2] + r2[3];
  const float mean = s1 * (1.f / 1280.f);
  float var = s2 * (1.f / 1280.f) - mean * mean;
  var = fmaxf(var, 0.f);
  const float rs = rsqrtf(var + 1e-5f);
#pragma unroll
  for (int i = 0; i < 5; i++) {
    int c = tid + i * 256;
    float y = (v[i] - mean) * rs * sc[c] + bi[c];
    xf[base + c] = y;
    xh[base + c] = f2bf(y);
  }
}

// ---------------- host launcher -------------------------------------------
extern "C" void kernel_launch(void* const* d_in, const int* in_sizes, int n_in,
                              void* d_out, int out_size, void* d_ws, size_t ws_size,
                              hipStream_t stream) {
  const float* data = (const float*)d_in[0];
  const float* phy  = (const float*)d_in[1];
  const float* Wi1  = (const float*)d_in[2];
  const float* bi1  = (const float*)d_in[3];
  const float* Wi2  = (const float*)d_in[4];
  const float* bi2  = (const float*)d_in[5];
  const float* Wo1  = (const float*)d_in[6];
  const float* bo1  = (const float*)d_in[7];
  const float* Wo2  = (const float*)d_in[8];
  const float* bo2  = (const float*)d_in[9];
  const float* We1  = (const float*)d_in[10];
  const float* be1  = (const float*)d_in[11];
  const float* We2  = (const float*)d_in[12];
  const float* be2  = (const float*)d_in[13];
  const float* Wfm  = (const float*)d_in[14];
  const float* bfm  = (const float*)d_in[15];
  const float* Wg1  = (const float*)d_in[16];
  const float* bg1  = (const float*)d_in[17];
  const float* Wg2  = (const float*)d_in[18];
  const float* bg2  = (const float*)d_in[19];
  const float* Wq   = (const float*)d_in[20];
  const float* bq   = (const float*)d_in[21];
  const float* Wk   = (const float*)d_in[22];
  const float* bk   = (const float*)d_in[23];
  const float* Wv   = (const float*)d_in[24];
  const float* bv   = (const float*)d_in[25];
  const float* Woa  = (const float*)d_in[26];
  const float* boa  = (const float*)d_in[27];
  const float* ln1s = (const float*)d_in[28];
  const float* ln1b = (const float*)d_in[29];
  const float* ln2s = (const float*)d_in[30];
  const float* ln2b = (const float*)d_in[31];
  const float* Wff1 = (const float*)d_in[32];
  const float* bff1 = (const float*)d_in[33];
  const float* Wff2 = (const float*)d_in[34];
  const float* bff2 = (const float*)d_in[35];
  const float* Wout = (const float*)d_in[36];
  const float* bout = (const float*)d_in[37];

  char* ws = (char*)d_ws;
  u16* wt = (u16*)ws;
  float* fb  = (float*)(ws + FOFF);
  float* z_t = fb + F_ZT;
  float* xf  = fb + F_XF;
  float* fq  = fb + F_Q;
  float* fk  = fb + F_K;
  float* fv  = fb + F_V;
  float* t1  = fb + F_T1;
  bf16* hb  = (bf16*)(ws + HOFF);
  bf16* xh  = hb + H_XH;
  bf16* oh  = hb + H_OH;
  bf16* ffh = hb + H_FF;

  float* out = (float*)d_out;
  float* out_pred = out;            // 480 x 160
  float* out_mu   = out + 76800;    // 480 x 64
  float* out_z    = out + 107520;   // 480 x 64

  ode_kernel<<<480, 64, 0, stream>>>(data, phy, Wi1, bi1, Wi2, bi2,
                                     Wo1, bo1, Wo2, bo2, z_t, out_z);
  cd_kernel<<<9600, 64, 0, stream>>>(data, z_t, We1, be1, We2, be2,
                                     Wfm, bfm, Wg1, bg1, Wg2, bg2,
                                     xf, xh, out_mu);

  for (int l = 0; l < 6; l++) {
    transpose_layer_kernel<<<13000, 256, 0, stream>>>(
        Wq, Wk, Wv, Woa, Wff1, Wff2, Wout, wt, l);
    // QKV (z = 0,1,2): 240 blocks
    gemm_bt<0><<<dim3(10, 8, 3), 256, 0, stream>>>(
        (const u16*)xh, wt + WT_Q, SLICE_DD,
        bq + l * 1280, bk + l * 1280, bv + l * 1280,
        fq, nullptr, 614400, 480, 1280, 1280);
    attn_kernel<<<384, 64, 0, stream>>>(fq, fk, fv, oh);
    gemm_bt<0><<<dim3(10, 8, 1), 256, 0, stream>>>(
        (const u16*)oh, wt + WT_O, 0,
        boa + l * 1280, boa + l * 1280, boa + l * 1280,
        t1, nullptr, 0, 480, 1280, 1280);
    ln_kernel<<<480, 256, 0, stream>>>(t1, xf, xh, ln1s + l * 1280, ln1b + l * 1280);
    gemm_bt<1><<<dim3(20, 8, 1), 256, 0, stream>>>(
        (const u16*)xh, wt + WT_F1, 0,
        bff1 + l * 2560, bff1 + l * 2560, bff1 + l * 2560,
        nullptr, ffh, 0, 480, 2560, 1280);
    gemm_bt<0><<<dim3(10, 8, 1), 256, 0, stream>>>(
        (const u16*)ffh, wt + WT_F2, 0,
        bff2 + l * 1280, bff2 + l * 1280, bff2 + l * 1280,
        t1, nullptr, 0, 480, 1280, 2560);
    ln_kernel<<<480, 256, 0, stream>>>(t1, xf, xh, ln2s + l * 1280, ln2b + l * 1280);
  }

  gemm_bt<0><<<dim3(2, 8, 1), 256, 0, stream>>>(
      (const u16*)xh, wt + WT_OUT, 0, bout, bout, bout,
      out_pred, nullptr, 0, 480, 160, 1280);
}